// Round 15
// baseline (517.629 us; speedup 1.0000x reference)
//
#include <hip/hip_runtime.h>

typedef unsigned short u16;
typedef float f32x4 __attribute__((ext_vector_type(4)));
typedef __bf16 bf16x8 __attribute__((ext_vector_type(8)));
typedef unsigned int u32x4 __attribute__((ext_vector_type(4)));
typedef u16 u16x4 __attribute__((ext_vector_type(4)));

#define S_ 2048
#define D_ 1024
#define H_ 16
#define HD_ 64

#define WAITV(N) asm volatile("s_waitcnt vmcnt(" #N ")" ::: "memory")
#define BAR() __builtin_amdgcn_s_barrier()
#define SFENCE() __builtin_amdgcn_sched_barrier(0)

__device__ __forceinline__ u16 f2bf(float f) {
  unsigned int u = __builtin_bit_cast(unsigned int, f);
  u += 0x7fffu + ((u >> 16) & 1u);
  return (u16)(u >> 16);
}

__device__ __forceinline__ f32x4 mfma16(bf16x8 a, bf16x8 b, f32x4 c) {
  return __builtin_amdgcn_mfma_f32_16x16x32_bf16(a, b, c, 0, 0, 0);
}

// 2^x via v_exp_f32 (s_nop covers the TRANS->VALU hazard window)
__device__ __forceinline__ float ex2(float x) {
  float r;
  asm("v_exp_f32 %0, %1\n\ts_nop 1" : "=v"(r) : "v"(x));
  return r;
}

// async global->LDS, 16B per lane. LDS dest must be linear in lane order.
__device__ __forceinline__ void gld_lds16(const u16* g, u16* l) {
  __builtin_amdgcn_global_load_lds((const __attribute__((address_space(1))) void*)g,
                                   (__attribute__((address_space(3))) void*)l, 16, 0, 0);
}

// ---------- prep: cast inputs + cast/transpose all weights (one launch) ----------
__global__ __launch_bounds__(256) void prep_kernel(
    const float* __restrict__ hs, const float* __restrict__ kn, const float* __restrict__ Wq,
    const float* __restrict__ Wkk, const float* __restrict__ Wvk, const float* __restrict__ Wkm,
    const float* __restrict__ Wvm, const float* __restrict__ Wo, u16* __restrict__ hs_bf,
    u16* __restrict__ kn_bf, u16* __restrict__ WqT, u16* __restrict__ WkvkT,
    u16* __restrict__ WkvmT, u16* __restrict__ WoT, int n4) {
  __shared__ float tile[32][33];
  int b = blockIdx.x;
  if (b < 4096) {  // cast path
    int i = b * 256 + threadIdx.x;
    const float* s;
    u16* d;
    int j;
    if (i < n4) { s = hs; d = hs_bf; j = i; }
    else { j = i - n4; if (j >= n4) return; s = kn; d = kn_bf; }
    f32x4 v = *(const f32x4*)(s + (size_t)j * 4);
    u16x4 o;
    o[0] = f2bf(v[0]); o[1] = f2bf(v[1]); o[2] = f2bf(v[2]); o[3] = f2bf(v[3]);
    *(u16x4*)(d + (size_t)j * 4) = o;
    return;
  }
  int idx = b - 4096;
  int bc = idx & 31, y = idx >> 5;  // y in [0,224)
  const float* W;
  u16* WT;
  int R, br;
  const size_t HM = (size_t)1024 * 1024;
  if (y < 64) { W = Wq; WT = WqT; R = 2048; br = y; }
  else {
    R = 1024; br = y & 31;
    switch ((y - 64) >> 5) {
      case 0: W = Wkk; WT = WkvkT; break;
      case 1: W = Wvk; WT = WkvkT + HM; break;
      case 2: W = Wkm; WT = WkvmT; break;
      case 3: W = Wvm; WT = WkvmT + HM; break;
      default: W = Wo; WT = WoT; break;
    }
  }
  int tx = threadIdx.x & 31, ty = threadIdx.x >> 5;
#pragma unroll
  for (int i = 0; i < 4; ++i)
    tile[ty + i * 8][tx] = W[(size_t)(br * 32 + ty + i * 8) * 1024 + bc * 32 + tx];
  __syncthreads();
#pragma unroll
  for (int i = 0; i < 4; ++i)
    WT[(size_t)(bc * 32 + ty + i * 8) * R + br * 32 + tx] = f2bf(tile[tx][ty + i * 8]);
}

// ---------- GEMM body: (MI*32)x(NI*32) tile, BK=32, 4 waves, dbuf + counted vmcnt ----------
// MODE 0: bf16 row-major C via LDS epilogue | MODE 1: f32 via LDS epilogue (nt) |
// MODE 2: bf16 transposed vT[n][m], direct 8B stores
template <int MODE, int MI, int NI>
__device__ __forceinline__ void gemm_body(u16* smem, const u16* A0, const u16* A1, int ksplit,
                                          const u16* BT, void* Cp, int K, int ldc, int bn,
                                          int bm) {
  constexpr int BM = MI * 32, BN = NI * 32;
  u16* const As0 = smem;                 // [2][BM*32]
  u16* const Bs0 = smem + 2 * BM * 32;   // [2][BN*32]
  const int tid = threadIdx.x, l = tid & 63, w = tid >> 6;
  const int wm = w >> 1, wn = w & 1;
  f32x4 zf = {0.f, 0.f, 0.f, 0.f};
  f32x4 acc[MI][NI];
#pragma unroll
  for (int mi = 0; mi < MI; ++mi)
#pragma unroll
    for (int ni = 0; ni < NI; ++ni) acc[mi][ni] = zf;

  auto STAGE = [&](int b, int t) {
    int k0 = t * 32;
#pragma unroll
    for (int i = 0; i < MI / 2; ++i) {  // A: BM rows x 4 chunks(16B), swizzled source
      int idx = tid + i * 256, r = idx >> 2, c = idx & 3;
      int sc = c ^ ((r >> 1) & 3);
      int k = k0 + sc * 8;
      const u16* src = (k < ksplit) ? (A0 + (size_t)(bm * BM + r) * D_ + k)
                                    : (A1 + (size_t)(bm * BM + r) * D_ + (k - ksplit));
      gld_lds16(src, As0 + b * BM * 32 + idx * 8);
    }
#pragma unroll
    for (int i = 0; i < NI / 2; ++i) {  // B
      int idx = tid + i * 256, r = idx >> 2, c = idx & 3;
      int sc = c ^ ((r >> 1) & 3);
      gld_lds16(BT + (size_t)(bn * BN + r) * K + k0 + sc * 8, Bs0 + b * BN * 32 + idx * 8);
    }
  };

  const int nt = K >> 5;
  STAGE(0, 0);
  int cur = 0;
  for (int t = 0; t < nt; ++t) {
    if (t + 1 < nt) {
      STAGE(cur ^ 1, t + 1);
      if constexpr (MI + NI == 8) { WAITV(4); }
      else if constexpr (MI + NI == 6) { WAITV(3); }
      else { WAITV(2); }
    } else {
      WAITV(0);
    }
    BAR(); SFENCE();
    const u16* Asc = As0 + cur * BM * 32;
    const u16* Bsc = Bs0 + cur * BN * 32;
    bf16x8 af[MI], bfr[NI];
#pragma unroll
    for (int mi = 0; mi < MI; ++mi) {
      int row = wm * (MI * 16) + mi * 16 + (l & 15);
      int slot = (l >> 4) ^ ((row >> 1) & 3);
      af[mi] = __builtin_bit_cast(bf16x8, *(const u32x4*)(Asc + row * 32 + slot * 8));
    }
#pragma unroll
    for (int ni = 0; ni < NI; ++ni) {
      int row = wn * (NI * 16) + ni * 16 + (l & 15);
      int slot = (l >> 4) ^ ((row >> 1) & 3);
      bfr[ni] = __builtin_bit_cast(bf16x8, *(const u32x4*)(Bsc + row * 32 + slot * 8));
    }
#pragma unroll
    for (int mi = 0; mi < MI; ++mi)
#pragma unroll
      for (int ni = 0; ni < NI; ++ni) acc[mi][ni] = mfma16(af[mi], bfr[ni], acc[mi][ni]);
    SFENCE(); BAR();
    cur ^= 1;
  }

  if constexpr (MODE == 2) {  // vT[n][m0..m0+3], 8B contiguous
#pragma unroll
    for (int mi = 0; mi < MI; ++mi)
#pragma unroll
      for (int ni = 0; ni < NI; ++ni) {
        u16x4 pk;
#pragma unroll
        for (int r = 0; r < 4; ++r) pk[r] = f2bf(acc[mi][ni][r]);
        int n = bn * BN + wn * (NI * 16) + ni * 16 + (l & 15);
        int m0 = bm * BM + wm * (MI * 16) + mi * 16 + (l >> 4) * 4;
        *(u16x4*)((u16*)Cp + (size_t)n * S_ + m0) = pk;
      }
  } else if constexpr (MODE == 0) {
    // bf16 epilogue via LDS: pad row stride 144 u16
    __syncthreads();  // all compute done -> safe to alias staging LDS
    u16* Cs = smem;   // [BM][144]
#pragma unroll
    for (int mi = 0; mi < MI; ++mi)
#pragma unroll
      for (int ni = 0; ni < NI; ++ni)
#pragma unroll
        for (int r = 0; r < 4; ++r) {
          int row = wm * (MI * 16) + mi * 16 + (l >> 4) * 4 + r;
          int col = wn * (NI * 16) + ni * 16 + (l & 15);
          Cs[row * 144 + col] = f2bf(acc[mi][ni][r]);
        }
    __syncthreads();
    constexpr int CPR = BN / 8;  // 16B chunks per row
#pragma unroll
    for (int i = 0; i < BM * CPR / 256; ++i) {
      int idx = tid + i * 256;
      int lr = idx / CPR, cc = idx % CPR;
      u32x4 v = *(const u32x4*)(Cs + lr * 144 + cc * 8);
      *(u32x4*)((u16*)Cp + (size_t)(bm * BM + lr) * ldc + bn * BN + cc * 8) = v;
    }
  } else {
    // f32 epilogue via LDS: pad row stride 136 f32
    __syncthreads();
    float* Cs = (float*)smem;  // [BM][136]
#pragma unroll
    for (int mi = 0; mi < MI; ++mi)
#pragma unroll
      for (int ni = 0; ni < NI; ++ni)
#pragma unroll
        for (int r = 0; r < 4; ++r) {
          int row = wm * (MI * 16) + mi * 16 + (l >> 4) * 4 + r;
          int col = wn * (NI * 16) + ni * 16 + (l & 15);
          Cs[row * 136 + col] = acc[mi][ni][r];
        }
    __syncthreads();
    constexpr int CPR = BN / 4;  // 16B chunks per row
#pragma unroll
    for (int i = 0; i < BM * CPR / 256; ++i) {
      int idx = tid + i * 256;
      int lr = idx / CPR, cc = idx % CPR;
      f32x4 v = *(const f32x4*)(Cs + lr * 136 + cc * 4);
      __builtin_nontemporal_store(v, (f32x4*)((float*)Cp + (size_t)(bm * BM + lr) * ldc +
                                              bn * BN + cc * 4));
    }
  }
}

// ---------- fused projections: work-balanced 768-block grid (R12, confirmed) ----------
__global__ __launch_bounds__(256) void proj_gemm(const u16* __restrict__ hs_bf,
                                                 const u16* __restrict__ kn_bf,
                                                 const u16* __restrict__ WqT,
                                                 const u16* __restrict__ WkvkT,
                                                 const u16* __restrict__ WkvmT,
                                                 u16* __restrict__ qb, u16* __restrict__ kk,
                                                 u16* __restrict__ km, u16* __restrict__ vkT,
                                                 u16* __restrict__ vmT) {
  __shared__ __attribute__((aligned(16))) u16 smem[18432];  // 36.9KB -> 4 blocks/CU
  int bid = blockIdx.x;  // 768 blocks
  int xcd = bid & 7, ixd = bid >> 3;  // ixd in [0,96)
  int bm, bn;
  if (ixd < 16) {        // Q-GEMM (2x work): ixd 0..15 -> CUs 0..15
    bm = xcd * 2 + (ixd >> 3);
    bn = ixd & 7;
  } else if (ixd >= 64 && ixd < 80) {
    return;              // no-op filler: keeps round 3 off the Q-CUs
  } else {
    int s = (ixd < 64) ? (ixd - 16) : (48 + (ixd - 80));  // short index 0..63
    bm = xcd * 2 + (s >> 5);
    bn = 8 + (s & 31);
  }
  const size_t HM = (size_t)1024 * 1024;
  const int BIG = 1 << 30;
  if (bn < 8) {
    gemm_body<0, 4, 4>(smem, hs_bf, kn_bf, 1024, WqT, qb, 2048, 1024, bn, bm);
  } else if (bn < 16) {
    gemm_body<0, 4, 4>(smem, kn_bf, kn_bf, BIG, WkvkT, kk, 1024, 1024, bn - 8, bm);
  } else if (bn < 24) {
    gemm_body<2, 4, 4>(smem, kn_bf, kn_bf, BIG, WkvkT + HM, vkT, 1024, 0, bn - 16, bm);
  } else if (bn < 32) {
    gemm_body<0, 4, 4>(smem, hs_bf, hs_bf, BIG, WkvmT, km, 1024, 1024, bn - 24, bm);
  } else {
    gemm_body<2, 4, 4>(smem, hs_bf, hs_bf, BIG, WkvmT + HM, vmT, 1024, 0, bn - 32, bm);
  }
}

// ---------- output GEMM: 64x64 tiles, 512 blocks (2/CU), XCD-swizzled ----------
__global__ __launch_bounds__(256) void out_gemm(const u16* __restrict__ aob,
                                                const u16* __restrict__ WoT,
                                                float* __restrict__ out) {
  __shared__ __attribute__((aligned(16))) u16 smem[17408];  // max(stage 16KB, Cs 64*136*4B)
  int bid = blockIdx.x;  // 512 blocks
  int xcd = bid & 7, i = bid >> 3;           // i in [0,64)
  int bm = xcd * 4 + (i >> 4), bn = i & 15;  // bm in [0,32), bn in [0,16)
  gemm_body<1, 2, 2>(smem, aob, aob, 1 << 30, WoT, out, 1024, 1024, bn, bm);
}

// ---------- async 64x64 bf16 tile stage, 512 threads, 1 issue/thread ----------
__device__ __forceinline__ void stage_async64_t512(u16* dst, const u16* src, int stride,
                                                   int tid) {
  int ci = tid;  // 16B chunk index 0..511
  int r = ci >> 3, c = ci & 7;
  int sc = c ^ (r & 7);
  gld_lds16(src + (size_t)r * stride + sc * 8, dst + ci * 8);
}

__device__ __forceinline__ bf16x8 ld_frag64(const u16* lds, int rowbase, int chunkbase, int l) {
  int row = rowbase + (l & 15);
  int chunk = chunkbase + (l >> 4);
  int slot = chunk ^ (row & 7);
  return __builtin_bit_cast(bf16x8, *(const u32x4*)(lds + row * 64 + slot * 8));
}

// ---------- fused attention + DISTRIBUTED causal-complement zero fill ----------
// 512 blocks x 512 threads; key-split wave pairs (R13); pairwise both passes (R14).
// NEW: (1) zero fill distributed: block qt zeroes the complement of row-tile 31-qt,
// one 64-col stripe per pass-2 pair (matches pair count; clamped duplicate on the
// last pair) -> the HBM write stream is fed continuously instead of end-bursts.
// vmcnt: stores/pair = 4 scores + 4 zeros -> WAITV(8). (2) pass-1 ring-6 over the
// unified krv buffer: prefetch depth 2 pairs, tight WAITV(2)/WAITV(0).
__global__ __launch_bounds__(512) void attn_kernel(const u16* __restrict__ qb,
                                                   const u16* __restrict__ kk,
                                                   const u16* __restrict__ km,
                                                   const u16* __restrict__ vkT,
                                                   const u16* __restrict__ vmT,
                                                   float* __restrict__ scores,
                                                   u16* __restrict__ ao) {
  const int fid = blockIdx.x;
  const int xcd = fid & 7, ixd = fid >> 3;  // ixd in [0,64)
  const int h = xcd * 2 + (ixd >> 5);       // 2 heads per XCD -> K/V L2-resident
  const int j = ixd & 31;
  const int a = j >> 1;
  // half 0: big,small,big,... ; half 1: small,big,small,... (complementary)
  const int qt = (((j & 1) ^ (ixd >> 5)) == 0) ? (31 - a) : a;
  const int tid = threadIdx.x, w = tid >> 6, l = tid & 63;
  const int wk = w & 3, kh = w >> 2;  // q-row group / key half
  const int nt = qt + 1;  // 64-key tiles per half
  const int NT = 2 * nt;  // always even, >= 2
  const int qrow0 = qt * 64;
  const int q16 = l & 15, c4 = l >> 4;
  const int qme = qrow0 + wk * 16 + q16;  // this lane's q-row
  const float sc2 = 0.04508422f;          // log2(e)/32

  __shared__ u16 krv[8 * 4096];  // pass1: ring-6 (slots 0-5); pass2: K slots 0-3, V slots 4-7
  __shared__ u16 ps[64 * 64];    // Q staging, then P tile
  __shared__ float stat[128];    // per-wave lsum handoff

  auto kptr = [&](int it) {
    int hf = it >= nt;
    int t = it - (hf ? nt : 0);
    const u16* kb = hf ? km : kk;
    return kb + (size_t)(t * 64) * 1024 + h * HD_;
  };
  auto vptr = [&](int it) {
    int hf = it >= nt;
    int t = it - (hf ? nt : 0);
    const u16* vb = hf ? vmT : vkT;
    return vb + (size_t)(h * HD_) * S_ + t * 64;
  };

  // stage Q into ps (sync, swizzled write): 512 chunks, 1 per thread
  {
    int r = tid >> 3, c = tid & 7;
    u32x4 v = *(const u32x4*)(qb + (size_t)(qrow0 + r) * D_ + h * HD_ + c * 8);
    *(u32x4*)(ps + r * 64 + ((c ^ (r & 7)) * 8)) = v;
  }
  __syncthreads();  // full drain: vmcnt clean for counted waits below
  bf16x8 qA0 = ld_frag64(ps, wk * 16, 0, l);
  bf16x8 qA1 = ld_frag64(ps, wk * 16, 4, l);
  __syncthreads();  // all Q-frag reads done before ps is reused in pass 2

  // ---- pass 1: lsum only (max-free); pairwise tiles, ring-6, depth-2-pair prefetch ----
  float aa[4] = {0.f, 0.f, 0.f, 0.f};
#pragma unroll
  for (int t = 0; t < 4; ++t)
    if (t < NT) stage_async64_t512(krv + (t % 6) * 4096, kptr(t), 1024, tid);
  for (int p = 0; p < NT; p += 2) {
    // after L(pair p): only L(pair p+2) (x2) newer, iff staged -> tight counted wait
    if (p + 2 < NT) { WAITV(2); } else { WAITV(0); }
    BAR(); SFENCE();
    if (p + 4 < NT) stage_async64_t512(krv + ((p + 4) % 6) * 4096, kptr(p + 4), 1024, tid);
    if (p + 5 < NT) stage_async64_t512(krv + ((p + 5) % 6) * 4096, kptr(p + 5), 1024, tid);
    __builtin_amdgcn_s_setprio(1);
#pragma unroll
    for (int half = 0; half < 2; ++half) {
      int it = p + half;
      const u16* ksb = krv + (it % 6) * 4096;
      int domask = (it == nt - 1) || (it == NT - 1);
      int tbase = (it - (it >= nt ? nt : 0)) * 64;
      f32x4 zfv = {0.f, 0.f, 0.f, 0.f};
#pragma unroll
      for (int jf = 0; jf < 2; ++jf) {
        int kf = kh * 2 + jf;
        f32x4 z = zfv;
        z = mfma16(ld_frag64(ksb, kf * 16, 0, l), qA0, z);
        z = mfma16(ld_frag64(ksb, kf * 16, 4, l), qA1, z);
#pragma unroll
        for (int r = 0; r < 4; ++r) {
          float v = z[r];
          if (domask) {
            int key = tbase + kf * 16 + c4 * 4 + r;
            if (key > qme) v = -1e30f;  // ex2 -> 0
          }
          aa[r] += ex2(v * sc2);
        }
      }
    }
    __builtin_amdgcn_s_setprio(0);
    SFENCE();
  }
  // wave-local sum over its 32 keys, then join across the key-split pair
  float psum = (aa[0] + aa[1]) + (aa[2] + aa[3]);
  psum += __shfl_xor(psum, 16, 64);
  psum += __shfl_xor(psum, 32, 64);
  if (l < 16) stat[w * 16 + l] = psum;
  __syncthreads();  // also: all waves done with pass-1 krv reads
  const float lsum = stat[wk * 16 + q16] + stat[(wk + 4) * 16 + q16];
  const float moff = __log2f(lsum);  // p = 2^(s*sc2 - moff)

  // ---- pass 2: pairwise; S recompute (own key half), scores + zero stripe, PV ----
  f32x4 zf = {0.f, 0.f, 0.f, 0.f};
  f32x4 o[4];
#pragma unroll
  for (int df = 0; df < 4; ++df) o[df] = zf;

  float* const srow0 = scores + ((size_t)h * S_ + qme) * (2 * S_) + c4 * 4;
  const int prow = wk * 16 + q16;
  const int swz8 = (q16 & 7) << 1;
  const int rt = 31 - qt;  // complementary row-tile whose zero region this block owns

  stage_async64_t512(krv + 0 * 4096, kptr(0), 1024, tid);
  stage_async64_t512(krv + 1 * 4096, kptr(1), 1024, tid);
  stage_async64_t512(krv + 4 * 4096, vptr(0), S_, tid);
  stage_async64_t512(krv + 5 * 4096, vptr(1), S_, tid);
  for (int p = 0; p < NT; p += 2) {
    // after L(pair p): Z(p-2) x4 + S(p-2) x4 newer -> WAITV(8); first pair: drain all
    if (p == 0) { WAITV(0); } else { WAITV(8); }
    BAR(); SFENCE();
    if (p + 2 < NT) {  // stage next pair (slots freed by compute(p-2), proven by BAR)
      stage_async64_t512(krv + ((p + 2) & 3) * 4096, kptr(p + 2), 1024, tid);
      stage_async64_t512(krv + ((p + 3) & 3) * 4096, kptr(p + 3), 1024, tid);
      stage_async64_t512(krv + (4 + ((p + 2) & 3)) * 4096, vptr(p + 2), S_, tid);
      stage_async64_t512(krv + (4 + ((p + 3) & 3)) * 4096, vptr(p + 3), S_, tid);
    }
    // zero stripe pp of row-tile rt's causal complement (4 x 16B nt per thread)
    if (qt > 0) {
      int pp = p >> 1;
      if (pp >= qt) pp = qt - 1;               // clamped duplicate on last pair (zeros: harmless)
      int col0 = (rt + 1) * 64 + pp * 64;      // <= 1984
      float* zb = scores + ((size_t)h * S_ + rt * 64) * (2 * S_) + col0;
      f32x4 zero = {0.f, 0.f, 0.f, 0.f};
      int idx = tid * 4;
#pragma unroll
      for (int e = 0; e < 4; ++e) {
        int id = idx + e;                      // 0..2047 over [row(64)][half(2)][cv(16)]
        int row = id >> 5, rem = id & 31, hf2 = rem >> 4, cv = rem & 15;
        __builtin_nontemporal_store(zero,
                                    (f32x4*)(zb + (size_t)row * (2 * S_) + hf2 * S_ + cv * 4));
      }
    }
#pragma unroll
    for (int half = 0; half < 2; ++half) {
      int it = p + half;
      int domask = (it == nt - 1) || (it == NT - 1);
      int hf = it >= nt;
      int tbase = (it - (hf ? nt : 0)) * 64;
      float pv[8];
      __builtin_amdgcn_s_setprio(1);
#pragma unroll
      for (int jf = 0; jf < 2; ++jf) {
        int kf = kh * 2 + jf;
        f32x4 z = zf;
        z = mfma16(ld_frag64(krv + (it & 3) * 4096, kf * 16, 0, l), qA0, z);
        z = mfma16(ld_frag64(krv + (it & 3) * 4096, kf * 16, 4, l), qA1, z);
#pragma unroll
        for (int r = 0; r < 4; ++r) {
          float v = z[r];
          if (domask) {
            int key = tbase + kf * 16 + c4 * 4 + r;
            if (key > qme) v = -1e30f;
          }
          pv[jf * 4 + r] = ex2(__builtin_fmaf(v, sc2, -moff));
        }
      }
      __builtin_amdgcn_s_setprio(0);
      // scores: 2 x 16B per lane (two waves cover the row's 256B contiguous)
      float* srow = srow0 + hf * S_ + tbase;
#pragma unroll
      for (int jf = 0; jf < 2; ++jf) {
        int kf = kh * 2 + jf;
        f32x4 s4 = {pv[jf * 4], pv[jf * 4 + 1], pv[jf * 4 + 2], pv[jf * 4 + 3]};
        *(f32x4*)(srow + kf * 16) = s4;
      }
      // ps: 2 x 8B per lane, 8B-slot XOR swizzle (bijective -> pair-disjoint);
      // wave-private rows+slots -> no barrier between tiles of a pair
#pragma unroll
      for (int jf = 0; jf < 2; ++jf) {
        int kf = kh * 2 + jf;
        u16x4 pk;
#pragma unroll
        for (int r = 0; r < 4; ++r) pk[r] = f2bf(pv[jf * 4 + r]);
        int slot8 = (kf * 4 + c4) ^ swz8;
        *(u16x4*)(ps + prow * 64 + slot8 * 4) = pk;
      }
      // PV over own 32 keys: one P-frag, 4 V-frags
      __builtin_amdgcn_s_setprio(1);
      {
        bf16x8 pa = ld_frag64(ps, wk * 16, kh * 4, l);
#pragma unroll
        for (int df = 0; df < 4; ++df)
          o[df] = mfma16(ld_frag64(krv + (4 + (it & 3)) * 4096, df * 16, kh * 4, l), pa, o[df]);
      }
      __builtin_amdgcn_s_setprio(0);
    }
    SFENCE();
  }

  // ---- join partial O across the key-split pair; kh=0 stores ao ----
  __syncthreads();                // all krv/ps reads complete
  float* obuf = (float*)krv;      // 16 KB scratch
  if (kh == 1) {
#pragma unroll
    for (int df = 0; df < 4; ++df)
#pragma unroll
      for (int r = 0; r < 4; ++r)
        obuf[((wk * 4 + df) * 16 + c4 * 4 + r) * 16 + q16] = o[df][r];
  }
  __syncthreads();
  if (kh == 0) {
#pragma unroll
    for (int df = 0; df < 4; ++df) {
      u16x4 pk;
#pragma unroll
      for (int r = 0; r < 4; ++r) {
        float t = o[df][r] + obuf[((wk * 4 + df) * 16 + c4 * 4 + r) * 16 + q16];
        pk[r] = f2bf(t);
      }
      *(u16x4*)(ao + (size_t)qme * D_ + h * HD_ + df * 16 + c4 * 4) = pk;
    }
  }
}

extern "C" void kernel_launch(void* const* d_in, const int* in_sizes, int n_in, void* d_out,
                              int out_size, void* d_ws, size_t ws_size, hipStream_t stream) {
  const float* hs = (const float*)d_in[0];
  const float* kn = (const float*)d_in[1];
  const float* Wq = (const float*)d_in[2];
  const float* Wkk = (const float*)d_in[3];
  const float* Wkm = (const float*)d_in[4];
  const float* Wvk = (const float*)d_in[5];
  const float* Wvm = (const float*)d_in[6];
  const float* Wo = (const float*)d_in[7];
  float* out = (float*)d_out;
  float* scores = out + (size_t)S_ * D_;

  const size_t M2 = (size_t)S_ * D_;  // 2M elems
  u16* ws = (u16*)d_ws;               // ~48 MB
  u16* hs_bf = ws;
  u16* kn_bf = hs_bf + M2;
  u16* WqT = kn_bf + M2;    // [1024][2048]
  u16* WkvkT = WqT + M2;    // [2048][1024]: rows 0-1023 Wkk^T, 1024-2047 Wvk^T
  u16* WkvmT = WkvkT + M2;  // same for mlp
  u16* WoT = WkvmT + M2;    // [1024][1024]
  u16* qb = WoT + M2 / 2;   // [2048][1024]
  u16* kk = qb + M2;        // [2048][1024] K_know
  u16* km = kk + M2;        // [2048][1024] K_mlp
  u16* vkT = km + M2;       // [1024][2048] per-head [h][hd][s]
  u16* vmT = vkT + M2;
  u16* aob = vmT + M2;

  int n4 = (int)(M2 / 4);
  prep_kernel<<<11264, 256, 0, stream>>>(hs, kn, Wq, Wkk, Wvk, Wkm, Wvm, Wo, hs_bf, kn_bf, WqT,
                                         WkvkT, WkvmT, WoT, n4);
  proj_gemm<<<768, 256, 0, stream>>>(hs_bf, kn_bf, WqT, WkvkT, WkvmT, qb, kk, km, vkT, vmT);
  attn_kernel<<<512, 512, 0, stream>>>(qb, kk, km, vkT, vmT, scores, aob);
  out_gemm<<<512, 256, 0, stream>>>(aob, WoT, out);
}

// Round 16
// 201.162 us; speedup vs baseline: 2.5732x; 2.5732x over previous
//
#include <hip/hip_runtime.h>

typedef unsigned short u16;
typedef float f32x4 __attribute__((ext_vector_type(4)));
typedef __bf16 bf16x8 __attribute__((ext_vector_type(8)));
typedef unsigned int u32x4 __attribute__((ext_vector_type(4)));
typedef u16 u16x4 __attribute__((ext_vector_type(4)));

#define S_ 2048
#define D_ 1024
#define H_ 16
#define HD_ 64

#define WAITV(N) asm volatile("s_waitcnt vmcnt(" #N ")" ::: "memory")
#define BAR() __builtin_amdgcn_s_barrier()
#define SFENCE() __builtin_amdgcn_sched_barrier(0)

__device__ __forceinline__ u16 f2bf(float f) {
  unsigned int u = __builtin_bit_cast(unsigned int, f);
  u += 0x7fffu + ((u >> 16) & 1u);
  return (u16)(u >> 16);
}

__device__ __forceinline__ f32x4 mfma16(bf16x8 a, bf16x8 b, f32x4 c) {
  return __builtin_amdgcn_mfma_f32_16x16x32_bf16(a, b, c, 0, 0, 0);
}

// 2^x via v_exp_f32 (s_nop covers the TRANS->VALU hazard window)
__device__ __forceinline__ float ex2(float x) {
  float r;
  asm("v_exp_f32 %0, %1\n\ts_nop 1" : "=v"(r) : "v"(x));
  return r;
}

// async global->LDS, 16B per lane. LDS dest must be linear in lane order.
__device__ __forceinline__ void gld_lds16(const u16* g, u16* l) {
  __builtin_amdgcn_global_load_lds((const __attribute__((address_space(1))) void*)g,
                                   (__attribute__((address_space(3))) void*)l, 16, 0, 0);
}

// ---------- prep: cast inputs + cast/transpose all weights (one launch) ----------
__global__ __launch_bounds__(256) void prep_kernel(
    const float* __restrict__ hs, const float* __restrict__ kn, const float* __restrict__ Wq,
    const float* __restrict__ Wkk, const float* __restrict__ Wvk, const float* __restrict__ Wkm,
    const float* __restrict__ Wvm, const float* __restrict__ Wo, u16* __restrict__ hs_bf,
    u16* __restrict__ kn_bf, u16* __restrict__ WqT, u16* __restrict__ WkvkT,
    u16* __restrict__ WkvmT, u16* __restrict__ WoT, int n4) {
  __shared__ float tile[32][33];
  int b = blockIdx.x;
  if (b < 4096) {  // cast path
    int i = b * 256 + threadIdx.x;
    const float* s;
    u16* d;
    int j;
    if (i < n4) { s = hs; d = hs_bf; j = i; }
    else { j = i - n4; if (j >= n4) return; s = kn; d = kn_bf; }
    f32x4 v = *(const f32x4*)(s + (size_t)j * 4);
    u16x4 o;
    o[0] = f2bf(v[0]); o[1] = f2bf(v[1]); o[2] = f2bf(v[2]); o[3] = f2bf(v[3]);
    *(u16x4*)(d + (size_t)j * 4) = o;
    return;
  }
  int idx = b - 4096;
  int bc = idx & 31, y = idx >> 5;  // y in [0,224)
  const float* W;
  u16* WT;
  int R, br;
  const size_t HM = (size_t)1024 * 1024;
  if (y < 64) { W = Wq; WT = WqT; R = 2048; br = y; }
  else {
    R = 1024; br = y & 31;
    switch ((y - 64) >> 5) {
      case 0: W = Wkk; WT = WkvkT; break;
      case 1: W = Wvk; WT = WkvkT + HM; break;
      case 2: W = Wkm; WT = WkvmT; break;
      case 3: W = Wvm; WT = WkvmT + HM; break;
      default: W = Wo; WT = WoT; break;
    }
  }
  int tx = threadIdx.x & 31, ty = threadIdx.x >> 5;
#pragma unroll
  for (int i = 0; i < 4; ++i)
    tile[ty + i * 8][tx] = W[(size_t)(br * 32 + ty + i * 8) * 1024 + bc * 32 + tx];
  __syncthreads();
#pragma unroll
  for (int i = 0; i < 4; ++i)
    WT[(size_t)(bc * 32 + ty + i * 8) * R + br * 32 + tx] = f2bf(tile[tx][ty + i * 8]);
}

// ---------- GEMM body: (MI*32)x(NI*32) tile, BK=32, 4 waves, dbuf + counted vmcnt ----------
// MODE 0: bf16 row-major C via LDS epilogue | MODE 1: f32 via LDS epilogue (nt) |
// MODE 2: bf16 transposed vT[n][m], direct 8B stores
template <int MODE, int MI, int NI>
__device__ __forceinline__ void gemm_body(u16* smem, const u16* A0, const u16* A1, int ksplit,
                                          const u16* BT, void* Cp, int K, int ldc, int bn,
                                          int bm) {
  constexpr int BM = MI * 32, BN = NI * 32;
  u16* const As0 = smem;                 // [2][BM*32]
  u16* const Bs0 = smem + 2 * BM * 32;   // [2][BN*32]
  const int tid = threadIdx.x, l = tid & 63, w = tid >> 6;
  const int wm = w >> 1, wn = w & 1;
  f32x4 zf = {0.f, 0.f, 0.f, 0.f};
  f32x4 acc[MI][NI];
#pragma unroll
  for (int mi = 0; mi < MI; ++mi)
#pragma unroll
    for (int ni = 0; ni < NI; ++ni) acc[mi][ni] = zf;

  auto STAGE = [&](int b, int t) {
    int k0 = t * 32;
#pragma unroll
    for (int i = 0; i < MI / 2; ++i) {  // A: BM rows x 4 chunks(16B), swizzled source
      int idx = tid + i * 256, r = idx >> 2, c = idx & 3;
      int sc = c ^ ((r >> 1) & 3);
      int k = k0 + sc * 8;
      const u16* src = (k < ksplit) ? (A0 + (size_t)(bm * BM + r) * D_ + k)
                                    : (A1 + (size_t)(bm * BM + r) * D_ + (k - ksplit));
      gld_lds16(src, As0 + b * BM * 32 + idx * 8);
    }
#pragma unroll
    for (int i = 0; i < NI / 2; ++i) {  // B
      int idx = tid + i * 256, r = idx >> 2, c = idx & 3;
      int sc = c ^ ((r >> 1) & 3);
      gld_lds16(BT + (size_t)(bn * BN + r) * K + k0 + sc * 8, Bs0 + b * BN * 32 + idx * 8);
    }
  };

  const int nt = K >> 5;
  STAGE(0, 0);
  int cur = 0;
  for (int t = 0; t < nt; ++t) {
    if (t + 1 < nt) {
      STAGE(cur ^ 1, t + 1);
      if constexpr (MI + NI == 8) { WAITV(4); }
      else if constexpr (MI + NI == 6) { WAITV(3); }
      else { WAITV(2); }
    } else {
      WAITV(0);
    }
    BAR(); SFENCE();
    const u16* Asc = As0 + cur * BM * 32;
    const u16* Bsc = Bs0 + cur * BN * 32;
    bf16x8 af[MI], bfr[NI];
#pragma unroll
    for (int mi = 0; mi < MI; ++mi) {
      int row = wm * (MI * 16) + mi * 16 + (l & 15);
      int slot = (l >> 4) ^ ((row >> 1) & 3);
      af[mi] = __builtin_bit_cast(bf16x8, *(const u32x4*)(Asc + row * 32 + slot * 8));
    }
#pragma unroll
    for (int ni = 0; ni < NI; ++ni) {
      int row = wn * (NI * 16) + ni * 16 + (l & 15);
      int slot = (l >> 4) ^ ((row >> 1) & 3);
      bfr[ni] = __builtin_bit_cast(bf16x8, *(const u32x4*)(Bsc + row * 32 + slot * 8));
    }
#pragma unroll
    for (int mi = 0; mi < MI; ++mi)
#pragma unroll
      for (int ni = 0; ni < NI; ++ni) acc[mi][ni] = mfma16(af[mi], bfr[ni], acc[mi][ni]);
    SFENCE(); BAR();
    cur ^= 1;
  }

  if constexpr (MODE == 2) {  // vT[n][m0..m0+3], 8B contiguous
#pragma unroll
    for (int mi = 0; mi < MI; ++mi)
#pragma unroll
      for (int ni = 0; ni < NI; ++ni) {
        u16x4 pk;
#pragma unroll
        for (int r = 0; r < 4; ++r) pk[r] = f2bf(acc[mi][ni][r]);
        int n = bn * BN + wn * (NI * 16) + ni * 16 + (l & 15);
        int m0 = bm * BM + wm * (MI * 16) + mi * 16 + (l >> 4) * 4;
        *(u16x4*)((u16*)Cp + (size_t)n * S_ + m0) = pk;
      }
  } else if constexpr (MODE == 0) {
    // bf16 epilogue via LDS: pad row stride 144 u16
    __syncthreads();  // all compute done -> safe to alias staging LDS
    u16* Cs = smem;   // [BM][144]
#pragma unroll
    for (int mi = 0; mi < MI; ++mi)
#pragma unroll
      for (int ni = 0; ni < NI; ++ni)
#pragma unroll
        for (int r = 0; r < 4; ++r) {
          int row = wm * (MI * 16) + mi * 16 + (l >> 4) * 4 + r;
          int col = wn * (NI * 16) + ni * 16 + (l & 15);
          Cs[row * 144 + col] = f2bf(acc[mi][ni][r]);
        }
    __syncthreads();
    constexpr int CPR = BN / 8;  // 16B chunks per row
#pragma unroll
    for (int i = 0; i < BM * CPR / 256; ++i) {
      int idx = tid + i * 256;
      int lr = idx / CPR, cc = idx % CPR;
      u32x4 v = *(const u32x4*)(Cs + lr * 144 + cc * 8);
      *(u32x4*)((u16*)Cp + (size_t)(bm * BM + lr) * ldc + bn * BN + cc * 8) = v;
    }
  } else {
    // f32 epilogue via LDS: pad row stride 136 f32
    __syncthreads();
    float* Cs = (float*)smem;  // [BM][136]
#pragma unroll
    for (int mi = 0; mi < MI; ++mi)
#pragma unroll
      for (int ni = 0; ni < NI; ++ni)
#pragma unroll
        for (int r = 0; r < 4; ++r) {
          int row = wm * (MI * 16) + mi * 16 + (l >> 4) * 4 + r;
          int col = wn * (NI * 16) + ni * 16 + (l & 15);
          Cs[row * 136 + col] = acc[mi][ni][r];
        }
    __syncthreads();
    constexpr int CPR = BN / 4;  // 16B chunks per row
#pragma unroll
    for (int i = 0; i < BM * CPR / 256; ++i) {
      int idx = tid + i * 256;
      int lr = idx / CPR, cc = idx % CPR;
      f32x4 v = *(const f32x4*)(Cs + lr * 136 + cc * 4);
      __builtin_nontemporal_store(v, (f32x4*)((float*)Cp + (size_t)(bm * BM + lr) * ldc +
                                              bn * BN + cc * 4));
    }
  }
}

// ---------- fused projections: work-balanced 768-block grid (R12, confirmed) ----------
__global__ __launch_bounds__(256) void proj_gemm(const u16* __restrict__ hs_bf,
                                                 const u16* __restrict__ kn_bf,
                                                 const u16* __restrict__ WqT,
                                                 const u16* __restrict__ WkvkT,
                                                 const u16* __restrict__ WkvmT,
                                                 u16* __restrict__ qb, u16* __restrict__ kk,
                                                 u16* __restrict__ km, u16* __restrict__ vkT,
                                                 u16* __restrict__ vmT) {
  __shared__ __attribute__((aligned(16))) u16 smem[18432];  // 36.9KB -> 4 blocks/CU
  int bid = blockIdx.x;  // 768 blocks
  int xcd = bid & 7, ixd = bid >> 3;  // ixd in [0,96)
  int bm, bn;
  if (ixd < 16) {        // Q-GEMM (2x work): ixd 0..15 -> CUs 0..15
    bm = xcd * 2 + (ixd >> 3);
    bn = ixd & 7;
  } else if (ixd >= 64 && ixd < 80) {
    return;              // no-op filler: keeps round 3 off the Q-CUs
  } else {
    int s = (ixd < 64) ? (ixd - 16) : (48 + (ixd - 80));  // short index 0..63
    bm = xcd * 2 + (s >> 5);
    bn = 8 + (s & 31);
  }
  const size_t HM = (size_t)1024 * 1024;
  const int BIG = 1 << 30;
  if (bn < 8) {
    gemm_body<0, 4, 4>(smem, hs_bf, kn_bf, 1024, WqT, qb, 2048, 1024, bn, bm);
  } else if (bn < 16) {
    gemm_body<0, 4, 4>(smem, kn_bf, kn_bf, BIG, WkvkT, kk, 1024, 1024, bn - 8, bm);
  } else if (bn < 24) {
    gemm_body<2, 4, 4>(smem, kn_bf, kn_bf, BIG, WkvkT + HM, vkT, 1024, 0, bn - 16, bm);
  } else if (bn < 32) {
    gemm_body<0, 4, 4>(smem, hs_bf, hs_bf, BIG, WkvmT, km, 1024, 1024, bn - 24, bm);
  } else {
    gemm_body<2, 4, 4>(smem, hs_bf, hs_bf, BIG, WkvmT + HM, vmT, 1024, 0, bn - 32, bm);
  }
}

// ---------- output GEMM: 64x64 tiles, 512 blocks (2/CU), XCD-swizzled ----------
__global__ __launch_bounds__(256) void out_gemm(const u16* __restrict__ aob,
                                                const u16* __restrict__ WoT,
                                                float* __restrict__ out) {
  __shared__ __attribute__((aligned(16))) u16 smem[17408];  // max(stage 16KB, Cs 64*136*4B)
  int bid = blockIdx.x;  // 512 blocks
  int xcd = bid & 7, i = bid >> 3;           // i in [0,64)
  int bm = xcd * 4 + (i >> 4), bn = i & 15;  // bm in [0,32), bn in [0,16)
  gemm_body<1, 2, 2>(smem, aob, aob, 1 << 30, WoT, out, 1024, 1024, bn, bm);
}

// ---------- async 64x64 bf16 tile stage, 512 threads, 1 issue/thread ----------
__device__ __forceinline__ void stage_async64_t512(u16* dst, const u16* src, int stride,
                                                   int tid) {
  int ci = tid;  // 16B chunk index 0..511
  int r = ci >> 3, c = ci & 7;
  int sc = c ^ (r & 7);
  gld_lds16(src + (size_t)r * stride + sc * 8, dst + ci * 8);
}

__device__ __forceinline__ bf16x8 ld_frag64(const u16* lds, int rowbase, int chunkbase, int l) {
  int row = rowbase + (l & 15);
  int chunk = chunkbase + (l >> 4);
  int slot = chunk ^ (row & 7);
  return __builtin_bit_cast(bf16x8, *(const u32x4*)(lds + row * 64 + slot * 8));
}

// ---------- fused attention + DISTRIBUTED causal-complement zero fill ----------
// 512 blocks x 512 threads; key-split wave pairs (R13); pairwise both passes (R14).
// Zero fill distributed (R15 concept, R16 FIX): per store instruction the 64 lanes
// must be CONSECUTIVE ids (id = e*512 + tid) -> 4 x 256B contiguous segments =
// whole 128B lines; the R15 mapping (id = tid*4+e) scattered 16B/64B -> nt
// partial-line RMW catastrophe (WRITE_SIZE +190MB, 2.5x regression).
__global__ __launch_bounds__(512) void attn_kernel(const u16* __restrict__ qb,
                                                   const u16* __restrict__ kk,
                                                   const u16* __restrict__ km,
                                                   const u16* __restrict__ vkT,
                                                   const u16* __restrict__ vmT,
                                                   float* __restrict__ scores,
                                                   u16* __restrict__ ao) {
  const int fid = blockIdx.x;
  const int xcd = fid & 7, ixd = fid >> 3;  // ixd in [0,64)
  const int h = xcd * 2 + (ixd >> 5);       // 2 heads per XCD -> K/V L2-resident
  const int j = ixd & 31;
  const int a = j >> 1;
  // half 0: big,small,big,... ; half 1: small,big,small,... (complementary)
  const int qt = (((j & 1) ^ (ixd >> 5)) == 0) ? (31 - a) : a;
  const int tid = threadIdx.x, w = tid >> 6, l = tid & 63;
  const int wk = w & 3, kh = w >> 2;  // q-row group / key half
  const int nt = qt + 1;  // 64-key tiles per half
  const int NT = 2 * nt;  // always even, >= 2
  const int qrow0 = qt * 64;
  const int q16 = l & 15, c4 = l >> 4;
  const int qme = qrow0 + wk * 16 + q16;  // this lane's q-row
  const float sc2 = 0.04508422f;          // log2(e)/32

  __shared__ u16 krv[8 * 4096];  // pass1: ring-6 (slots 0-5); pass2: K slots 0-3, V slots 4-7
  __shared__ u16 ps[64 * 64];    // Q staging, then P tile
  __shared__ float stat[128];    // per-wave lsum handoff

  auto kptr = [&](int it) {
    int hf = it >= nt;
    int t = it - (hf ? nt : 0);
    const u16* kb = hf ? km : kk;
    return kb + (size_t)(t * 64) * 1024 + h * HD_;
  };
  auto vptr = [&](int it) {
    int hf = it >= nt;
    int t = it - (hf ? nt : 0);
    const u16* vb = hf ? vmT : vkT;
    return vb + (size_t)(h * HD_) * S_ + t * 64;
  };

  // stage Q into ps (sync, swizzled write): 512 chunks, 1 per thread
  {
    int r = tid >> 3, c = tid & 7;
    u32x4 v = *(const u32x4*)(qb + (size_t)(qrow0 + r) * D_ + h * HD_ + c * 8);
    *(u32x4*)(ps + r * 64 + ((c ^ (r & 7)) * 8)) = v;
  }
  __syncthreads();  // full drain: vmcnt clean for counted waits below
  bf16x8 qA0 = ld_frag64(ps, wk * 16, 0, l);
  bf16x8 qA1 = ld_frag64(ps, wk * 16, 4, l);
  __syncthreads();  // all Q-frag reads done before ps is reused in pass 2

  // ---- pass 1: lsum only (max-free); pairwise tiles, ring-6, depth-2-pair prefetch ----
  float aa[4] = {0.f, 0.f, 0.f, 0.f};
#pragma unroll
  for (int t = 0; t < 4; ++t)
    if (t < NT) stage_async64_t512(krv + (t % 6) * 4096, kptr(t), 1024, tid);
  for (int p = 0; p < NT; p += 2) {
    // after L(pair p): only L(pair p+2) (x2) newer, iff staged -> tight counted wait
    if (p + 2 < NT) { WAITV(2); } else { WAITV(0); }
    BAR(); SFENCE();
    if (p + 4 < NT) stage_async64_t512(krv + ((p + 4) % 6) * 4096, kptr(p + 4), 1024, tid);
    if (p + 5 < NT) stage_async64_t512(krv + ((p + 5) % 6) * 4096, kptr(p + 5), 1024, tid);
    __builtin_amdgcn_s_setprio(1);
#pragma unroll
    for (int half = 0; half < 2; ++half) {
      int it = p + half;
      const u16* ksb = krv + (it % 6) * 4096;
      int domask = (it == nt - 1) || (it == NT - 1);
      int tbase = (it - (it >= nt ? nt : 0)) * 64;
      f32x4 zfv = {0.f, 0.f, 0.f, 0.f};
#pragma unroll
      for (int jf = 0; jf < 2; ++jf) {
        int kf = kh * 2 + jf;
        f32x4 z = zfv;
        z = mfma16(ld_frag64(ksb, kf * 16, 0, l), qA0, z);
        z = mfma16(ld_frag64(ksb, kf * 16, 4, l), qA1, z);
#pragma unroll
        for (int r = 0; r < 4; ++r) {
          float v = z[r];
          if (domask) {
            int key = tbase + kf * 16 + c4 * 4 + r;
            if (key > qme) v = -1e30f;  // ex2 -> 0
          }
          aa[r] += ex2(v * sc2);
        }
      }
    }
    __builtin_amdgcn_s_setprio(0);
    SFENCE();
  }
  // wave-local sum over its 32 keys, then join across the key-split pair
  float psum = (aa[0] + aa[1]) + (aa[2] + aa[3]);
  psum += __shfl_xor(psum, 16, 64);
  psum += __shfl_xor(psum, 32, 64);
  if (l < 16) stat[w * 16 + l] = psum;
  __syncthreads();  // also: all waves done with pass-1 krv reads
  const float lsum = stat[wk * 16 + q16] + stat[(wk + 4) * 16 + q16];
  const float moff = __log2f(lsum);  // p = 2^(s*sc2 - moff)

  // ---- pass 2: pairwise; S recompute (own key half), scores + zero stripe, PV ----
  f32x4 zf = {0.f, 0.f, 0.f, 0.f};
  f32x4 o[4];
#pragma unroll
  for (int df = 0; df < 4; ++df) o[df] = zf;

  float* const srow0 = scores + ((size_t)h * S_ + qme) * (2 * S_) + c4 * 4;
  const int prow = wk * 16 + q16;
  const int swz8 = (q16 & 7) << 1;
  const int rt = 31 - qt;  // complementary row-tile whose zero region this block owns

  stage_async64_t512(krv + 0 * 4096, kptr(0), 1024, tid);
  stage_async64_t512(krv + 1 * 4096, kptr(1), 1024, tid);
  stage_async64_t512(krv + 4 * 4096, vptr(0), S_, tid);
  stage_async64_t512(krv + 5 * 4096, vptr(1), S_, tid);
  for (int p = 0; p < NT; p += 2) {
    // after L(pair p): Z(p-2) x4 + S(p-2) x4 newer -> WAITV(8); first pair: drain all
    if (p == 0) { WAITV(0); } else { WAITV(8); }
    BAR(); SFENCE();
    if (p + 2 < NT) {  // stage next pair (slots freed by compute(p-2), proven by BAR)
      stage_async64_t512(krv + ((p + 2) & 3) * 4096, kptr(p + 2), 1024, tid);
      stage_async64_t512(krv + ((p + 3) & 3) * 4096, kptr(p + 3), 1024, tid);
      stage_async64_t512(krv + (4 + ((p + 2) & 3)) * 4096, vptr(p + 2), S_, tid);
      stage_async64_t512(krv + (4 + ((p + 3) & 3)) * 4096, vptr(p + 3), S_, tid);
    }
    // zero stripe pp of row-tile rt's causal complement (4 x 16B nt per thread;
    // id = e*512 + tid -> per-instruction lane-consecutive = full-line segments)
    if (qt > 0) {
      int pp = p >> 1;
      if (pp >= qt) pp = qt - 1;           // clamped duplicate on last pair (zeros: harmless)
      int col0 = (rt + 1) * 64 + pp * 64;  // <= 1984
      float* zb = scores + ((size_t)h * S_ + rt * 64) * (2 * S_) + col0;
      f32x4 zero = {0.f, 0.f, 0.f, 0.f};
#pragma unroll
      for (int e = 0; e < 4; ++e) {
        int id = e * 512 + tid;            // 0..2047 over [row(64)][half(2)][cv(16)]
        int row = id >> 5, rem = id & 31, hf2 = rem >> 4, cv = rem & 15;
        __builtin_nontemporal_store(zero,
                                    (f32x4*)(zb + (size_t)row * (2 * S_) + hf2 * S_ + cv * 4));
      }
    }
#pragma unroll
    for (int half = 0; half < 2; ++half) {
      int it = p + half;
      int domask = (it == nt - 1) || (it == NT - 1);
      int hf = it >= nt;
      int tbase = (it - (hf ? nt : 0)) * 64;
      float pv[8];
      __builtin_amdgcn_s_setprio(1);
#pragma unroll
      for (int jf = 0; jf < 2; ++jf) {
        int kf = kh * 2 + jf;
        f32x4 z = zf;
        z = mfma16(ld_frag64(krv + (it & 3) * 4096, kf * 16, 0, l), qA0, z);
        z = mfma16(ld_frag64(krv + (it & 3) * 4096, kf * 16, 4, l), qA1, z);
#pragma unroll
        for (int r = 0; r < 4; ++r) {
          float v = z[r];
          if (domask) {
            int key = tbase + kf * 16 + c4 * 4 + r;
            if (key > qme) v = -1e30f;
          }
          pv[jf * 4 + r] = ex2(__builtin_fmaf(v, sc2, -moff));
        }
      }
      __builtin_amdgcn_s_setprio(0);
      // scores: 2 x 16B per lane (two waves cover the row's 256B contiguous)
      float* srow = srow0 + hf * S_ + tbase;
#pragma unroll
      for (int jf = 0; jf < 2; ++jf) {
        int kf = kh * 2 + jf;
        f32x4 s4 = {pv[jf * 4], pv[jf * 4 + 1], pv[jf * 4 + 2], pv[jf * 4 + 3]};
        *(f32x4*)(srow + kf * 16) = s4;
      }
      // ps: 2 x 8B per lane, 8B-slot XOR swizzle (bijective -> pair-disjoint);
      // wave-private rows+slots -> no barrier between tiles of a pair
#pragma unroll
      for (int jf = 0; jf < 2; ++jf) {
        int kf = kh * 2 + jf;
        u16x4 pk;
#pragma unroll
        for (int r = 0; r < 4; ++r) pk[r] = f2bf(pv[jf * 4 + r]);
        int slot8 = (kf * 4 + c4) ^ swz8;
        *(u16x4*)(ps + prow * 64 + slot8 * 4) = pk;
      }
      // PV over own 32 keys: one P-frag, 4 V-frags
      __builtin_amdgcn_s_setprio(1);
      {
        bf16x8 pa = ld_frag64(ps, wk * 16, kh * 4, l);
#pragma unroll
        for (int df = 0; df < 4; ++df)
          o[df] = mfma16(ld_frag64(krv + (4 + (it & 3)) * 4096, df * 16, kh * 4, l), pa, o[df]);
      }
      __builtin_amdgcn_s_setprio(0);
    }
    SFENCE();
  }

  // ---- join partial O across the key-split pair; kh=0 stores ao ----
  __syncthreads();                // all krv/ps reads complete
  float* obuf = (float*)krv;      // 16 KB scratch
  if (kh == 1) {
#pragma unroll
    for (int df = 0; df < 4; ++df)
#pragma unroll
      for (int r = 0; r < 4; ++r)
        obuf[((wk * 4 + df) * 16 + c4 * 4 + r) * 16 + q16] = o[df][r];
  }
  __syncthreads();
  if (kh == 0) {
#pragma unroll
    for (int df = 0; df < 4; ++df) {
      u16x4 pk;
#pragma unroll
      for (int r = 0; r < 4; ++r) {
        float t = o[df][r] + obuf[((wk * 4 + df) * 16 + c4 * 4 + r) * 16 + q16];
        pk[r] = f2bf(t);
      }
      *(u16x4*)(ao + (size_t)qme * D_ + h * HD_ + df * 16 + c4 * 4) = pk;
    }
  }
}

extern "C" void kernel_launch(void* const* d_in, const int* in_sizes, int n_in, void* d_out,
                              int out_size, void* d_ws, size_t ws_size, hipStream_t stream) {
  const float* hs = (const float*)d_in[0];
  const float* kn = (const float*)d_in[1];
  const float* Wq = (const float*)d_in[2];
  const float* Wkk = (const float*)d_in[3];
  const float* Wkm = (const float*)d_in[4];
  const float* Wvk = (const float*)d_in[5];
  const float* Wvm = (const float*)d_in[6];
  const float* Wo = (const float*)d_in[7];
  float* out = (float*)d_out;
  float* scores = out + (size_t)S_ * D_;

  const size_t M2 = (size_t)S_ * D_;  // 2M elems
  u16* ws = (u16*)d_ws;               // ~48 MB
  u16* hs_bf = ws;
  u16* kn_bf = hs_bf + M2;
  u16* WqT = kn_bf + M2;    // [1024][2048]
  u16* WkvkT = WqT + M2;    // [2048][1024]: rows 0-1023 Wkk^T, 1024-2047 Wvk^T
  u16* WkvmT = WkvkT + M2;  // same for mlp
  u16* WoT = WkvmT + M2;    // [1024][1024]
  u16* qb = WoT + M2 / 2;   // [2048][1024]
  u16* kk = qb + M2;        // [2048][1024] K_know
  u16* km = kk + M2;        // [2048][1024] K_mlp
  u16* vkT = km + M2;       // [1024][2048] per-head [h][hd][s]
  u16* vmT = vkT + M2;
  u16* aob = vmT + M2;

  int n4 = (int)(M2 / 4);
  prep_kernel<<<11264, 256, 0, stream>>>(hs, kn, Wq, Wkk, Wvk, Wkm, Wvm, Wo, hs_bf, kn_bf, WqT,
                                         WkvkT, WkvmT, WoT, n4);
  proj_gemm<<<768, 256, 0, stream>>>(hs_bf, kn_bf, WqT, WkvkT, WkvmT, qb, kk, km, vkT, vmT);
  attn_kernel<<<512, 512, 0, stream>>>(qb, kk, km, vkT, vmT, scores, aob);
  out_gemm<<<512, 256, 0, stream>>>(aob, WoT, out);
}

// Round 17
// 180.461 us; speedup vs baseline: 2.8684x; 1.1147x over previous
//
#include <hip/hip_runtime.h>

typedef unsigned short u16;
typedef float f32x4 __attribute__((ext_vector_type(4)));
typedef __bf16 bf16x8 __attribute__((ext_vector_type(8)));
typedef unsigned int u32x4 __attribute__((ext_vector_type(4)));
typedef u16 u16x4 __attribute__((ext_vector_type(4)));

#define S_ 2048
#define D_ 1024
#define H_ 16
#define HD_ 64

#define WAITV(N) asm volatile("s_waitcnt vmcnt(" #N ")" ::: "memory")
#define BAR() __builtin_amdgcn_s_barrier()
#define SFENCE() __builtin_amdgcn_sched_barrier(0)

__device__ __forceinline__ u16 f2bf(float f) {
  unsigned int u = __builtin_bit_cast(unsigned int, f);
  u += 0x7fffu + ((u >> 16) & 1u);
  return (u16)(u >> 16);
}

__device__ __forceinline__ f32x4 mfma16(bf16x8 a, bf16x8 b, f32x4 c) {
  return __builtin_amdgcn_mfma_f32_16x16x32_bf16(a, b, c, 0, 0, 0);
}

// 2^x via v_exp_f32 (s_nop covers the TRANS->VALU hazard window)
__device__ __forceinline__ float ex2(float x) {
  float r;
  asm("v_exp_f32 %0, %1\n\ts_nop 1" : "=v"(r) : "v"(x));
  return r;
}

// async global->LDS, 16B per lane. LDS dest must be linear in lane order.
__device__ __forceinline__ void gld_lds16(const u16* g, u16* l) {
  __builtin_amdgcn_global_load_lds((const __attribute__((address_space(1))) void*)g,
                                   (__attribute__((address_space(3))) void*)l, 16, 0, 0);
}

// ---------- prep: cast inputs + cast/transpose all weights (one launch) ----------
__global__ __launch_bounds__(256) void prep_kernel(
    const float* __restrict__ hs, const float* __restrict__ kn, const float* __restrict__ Wq,
    const float* __restrict__ Wkk, const float* __restrict__ Wvk, const float* __restrict__ Wkm,
    const float* __restrict__ Wvm, const float* __restrict__ Wo, u16* __restrict__ hs_bf,
    u16* __restrict__ kn_bf, u16* __restrict__ WqT, u16* __restrict__ WkvkT,
    u16* __restrict__ WkvmT, u16* __restrict__ WoT, int n4) {
  __shared__ float tile[32][33];
  int b = blockIdx.x;
  if (b < 4096) {  // cast path
    int i = b * 256 + threadIdx.x;
    const float* s;
    u16* d;
    int j;
    if (i < n4) { s = hs; d = hs_bf; j = i; }
    else { j = i - n4; if (j >= n4) return; s = kn; d = kn_bf; }
    f32x4 v = *(const f32x4*)(s + (size_t)j * 4);
    u16x4 o;
    o[0] = f2bf(v[0]); o[1] = f2bf(v[1]); o[2] = f2bf(v[2]); o[3] = f2bf(v[3]);
    *(u16x4*)(d + (size_t)j * 4) = o;
    return;
  }
  int idx = b - 4096;
  int bc = idx & 31, y = idx >> 5;  // y in [0,224)
  const float* W;
  u16* WT;
  int R, br;
  const size_t HM = (size_t)1024 * 1024;
  if (y < 64) { W = Wq; WT = WqT; R = 2048; br = y; }
  else {
    R = 1024; br = y & 31;
    switch ((y - 64) >> 5) {
      case 0: W = Wkk; WT = WkvkT; break;
      case 1: W = Wvk; WT = WkvkT + HM; break;
      case 2: W = Wkm; WT = WkvmT; break;
      case 3: W = Wvm; WT = WkvmT + HM; break;
      default: W = Wo; WT = WoT; break;
    }
  }
  int tx = threadIdx.x & 31, ty = threadIdx.x >> 5;
#pragma unroll
  for (int i = 0; i < 4; ++i)
    tile[ty + i * 8][tx] = W[(size_t)(br * 32 + ty + i * 8) * 1024 + bc * 32 + tx];
  __syncthreads();
#pragma unroll
  for (int i = 0; i < 4; ++i)
    WT[(size_t)(bc * 32 + ty + i * 8) * R + br * 32 + tx] = f2bf(tile[tx][ty + i * 8]);
}

// ---------- GEMM body: (MI*32)x(NI*32) tile, BK=32, 4 waves, dbuf + counted vmcnt ----------
// MODE 0: bf16 row-major C via LDS epilogue | MODE 1: f32 via LDS epilogue (nt) |
// MODE 2: bf16 transposed vT[n][m], direct 8B stores
template <int MODE, int MI, int NI>
__device__ __forceinline__ void gemm_body(u16* smem, const u16* A0, const u16* A1, int ksplit,
                                          const u16* BT, void* Cp, int K, int ldc, int bn,
                                          int bm) {
  constexpr int BM = MI * 32, BN = NI * 32;
  u16* const As0 = smem;                 // [2][BM*32]
  u16* const Bs0 = smem + 2 * BM * 32;   // [2][BN*32]
  const int tid = threadIdx.x, l = tid & 63, w = tid >> 6;
  const int wm = w >> 1, wn = w & 1;
  f32x4 zf = {0.f, 0.f, 0.f, 0.f};
  f32x4 acc[MI][NI];
#pragma unroll
  for (int mi = 0; mi < MI; ++mi)
#pragma unroll
    for (int ni = 0; ni < NI; ++ni) acc[mi][ni] = zf;

  auto STAGE = [&](int b, int t) {
    int k0 = t * 32;
#pragma unroll
    for (int i = 0; i < MI / 2; ++i) {  // A: BM rows x 4 chunks(16B), swizzled source
      int idx = tid + i * 256, r = idx >> 2, c = idx & 3;
      int sc = c ^ ((r >> 1) & 3);
      int k = k0 + sc * 8;
      const u16* src = (k < ksplit) ? (A0 + (size_t)(bm * BM + r) * D_ + k)
                                    : (A1 + (size_t)(bm * BM + r) * D_ + (k - ksplit));
      gld_lds16(src, As0 + b * BM * 32 + idx * 8);
    }
#pragma unroll
    for (int i = 0; i < NI / 2; ++i) {  // B
      int idx = tid + i * 256, r = idx >> 2, c = idx & 3;
      int sc = c ^ ((r >> 1) & 3);
      gld_lds16(BT + (size_t)(bn * BN + r) * K + k0 + sc * 8, Bs0 + b * BN * 32 + idx * 8);
    }
  };

  const int nt = K >> 5;
  STAGE(0, 0);
  int cur = 0;
  for (int t = 0; t < nt; ++t) {
    if (t + 1 < nt) {
      STAGE(cur ^ 1, t + 1);
      if constexpr (MI + NI == 8) { WAITV(4); }
      else if constexpr (MI + NI == 6) { WAITV(3); }
      else { WAITV(2); }
    } else {
      WAITV(0);
    }
    BAR(); SFENCE();
    const u16* Asc = As0 + cur * BM * 32;
    const u16* Bsc = Bs0 + cur * BN * 32;
    bf16x8 af[MI], bfr[NI];
#pragma unroll
    for (int mi = 0; mi < MI; ++mi) {
      int row = wm * (MI * 16) + mi * 16 + (l & 15);
      int slot = (l >> 4) ^ ((row >> 1) & 3);
      af[mi] = __builtin_bit_cast(bf16x8, *(const u32x4*)(Asc + row * 32 + slot * 8));
    }
#pragma unroll
    for (int ni = 0; ni < NI; ++ni) {
      int row = wn * (NI * 16) + ni * 16 + (l & 15);
      int slot = (l >> 4) ^ ((row >> 1) & 3);
      bfr[ni] = __builtin_bit_cast(bf16x8, *(const u32x4*)(Bsc + row * 32 + slot * 8));
    }
#pragma unroll
    for (int mi = 0; mi < MI; ++mi)
#pragma unroll
      for (int ni = 0; ni < NI; ++ni) acc[mi][ni] = mfma16(af[mi], bfr[ni], acc[mi][ni]);
    SFENCE(); BAR();
    cur ^= 1;
  }

  if constexpr (MODE == 2) {  // vT[n][m0..m0+3], 8B contiguous
#pragma unroll
    for (int mi = 0; mi < MI; ++mi)
#pragma unroll
      for (int ni = 0; ni < NI; ++ni) {
        u16x4 pk;
#pragma unroll
        for (int r = 0; r < 4; ++r) pk[r] = f2bf(acc[mi][ni][r]);
        int n = bn * BN + wn * (NI * 16) + ni * 16 + (l & 15);
        int m0 = bm * BM + wm * (MI * 16) + mi * 16 + (l >> 4) * 4;
        *(u16x4*)((u16*)Cp + (size_t)n * S_ + m0) = pk;
      }
  } else if constexpr (MODE == 0) {
    // bf16 epilogue via LDS: pad row stride 144 u16
    __syncthreads();  // all compute done -> safe to alias staging LDS
    u16* Cs = smem;   // [BM][144]
#pragma unroll
    for (int mi = 0; mi < MI; ++mi)
#pragma unroll
      for (int ni = 0; ni < NI; ++ni)
#pragma unroll
        for (int r = 0; r < 4; ++r) {
          int row = wm * (MI * 16) + mi * 16 + (l >> 4) * 4 + r;
          int col = wn * (NI * 16) + ni * 16 + (l & 15);
          Cs[row * 144 + col] = f2bf(acc[mi][ni][r]);
        }
    __syncthreads();
    constexpr int CPR = BN / 8;  // 16B chunks per row
#pragma unroll
    for (int i = 0; i < BM * CPR / 256; ++i) {
      int idx = tid + i * 256;
      int lr = idx / CPR, cc = idx % CPR;
      u32x4 v = *(const u32x4*)(Cs + lr * 144 + cc * 8);
      *(u32x4*)((u16*)Cp + (size_t)(bm * BM + lr) * ldc + bn * BN + cc * 8) = v;
    }
  } else {
    // f32 epilogue via LDS: pad row stride 136 f32
    __syncthreads();
    float* Cs = (float*)smem;  // [BM][136]
#pragma unroll
    for (int mi = 0; mi < MI; ++mi)
#pragma unroll
      for (int ni = 0; ni < NI; ++ni)
#pragma unroll
        for (int r = 0; r < 4; ++r) {
          int row = wm * (MI * 16) + mi * 16 + (l >> 4) * 4 + r;
          int col = wn * (NI * 16) + ni * 16 + (l & 15);
          Cs[row * 136 + col] = acc[mi][ni][r];
        }
    __syncthreads();
    constexpr int CPR = BN / 4;  // 16B chunks per row
#pragma unroll
    for (int i = 0; i < BM * CPR / 256; ++i) {
      int idx = tid + i * 256;
      int lr = idx / CPR, cc = idx % CPR;
      f32x4 v = *(const f32x4*)(Cs + lr * 136 + cc * 4);
      __builtin_nontemporal_store(v, (f32x4*)((float*)Cp + (size_t)(bm * BM + lr) * ldc +
                                              bn * BN + cc * 4));
    }
  }
}

// ---------- fused projections: work-balanced 768-block grid (R12, confirmed) ----------
__global__ __launch_bounds__(256) void proj_gemm(const u16* __restrict__ hs_bf,
                                                 const u16* __restrict__ kn_bf,
                                                 const u16* __restrict__ WqT,
                                                 const u16* __restrict__ WkvkT,
                                                 const u16* __restrict__ WkvmT,
                                                 u16* __restrict__ qb, u16* __restrict__ kk,
                                                 u16* __restrict__ km, u16* __restrict__ vkT,
                                                 u16* __restrict__ vmT) {
  __shared__ __attribute__((aligned(16))) u16 smem[18432];  // 36.9KB -> 4 blocks/CU
  int bid = blockIdx.x;  // 768 blocks
  int xcd = bid & 7, ixd = bid >> 3;  // ixd in [0,96)
  int bm, bn;
  if (ixd < 16) {        // Q-GEMM (2x work): ixd 0..15 -> CUs 0..15
    bm = xcd * 2 + (ixd >> 3);
    bn = ixd & 7;
  } else if (ixd >= 64 && ixd < 80) {
    return;              // no-op filler: keeps round 3 off the Q-CUs
  } else {
    int s = (ixd < 64) ? (ixd - 16) : (48 + (ixd - 80));  // short index 0..63
    bm = xcd * 2 + (s >> 5);
    bn = 8 + (s & 31);
  }
  const size_t HM = (size_t)1024 * 1024;
  const int BIG = 1 << 30;
  if (bn < 8) {
    gemm_body<0, 4, 4>(smem, hs_bf, kn_bf, 1024, WqT, qb, 2048, 1024, bn, bm);
  } else if (bn < 16) {
    gemm_body<0, 4, 4>(smem, kn_bf, kn_bf, BIG, WkvkT, kk, 1024, 1024, bn - 8, bm);
  } else if (bn < 24) {
    gemm_body<2, 4, 4>(smem, kn_bf, kn_bf, BIG, WkvkT + HM, vkT, 1024, 0, bn - 16, bm);
  } else if (bn < 32) {
    gemm_body<0, 4, 4>(smem, hs_bf, hs_bf, BIG, WkvmT, km, 1024, 1024, bn - 24, bm);
  } else {
    gemm_body<2, 4, 4>(smem, hs_bf, hs_bf, BIG, WkvmT + HM, vmT, 1024, 0, bn - 32, bm);
  }
}

// ---------- output GEMM: 64x64 tiles, 512 blocks (2/CU), XCD-swizzled ----------
__global__ __launch_bounds__(256) void out_gemm(const u16* __restrict__ aob,
                                                const u16* __restrict__ WoT,
                                                float* __restrict__ out) {
  __shared__ __attribute__((aligned(16))) u16 smem[17408];  // max(stage 16KB, Cs 64*136*4B)
  int bid = blockIdx.x;  // 512 blocks
  int xcd = bid & 7, i = bid >> 3;           // i in [0,64)
  int bm = xcd * 4 + (i >> 4), bn = i & 15;  // bm in [0,32), bn in [0,16)
  gemm_body<1, 2, 2>(smem, aob, aob, 1 << 30, WoT, out, 1024, 1024, bn, bm);
}

// ---------- async 64x64 bf16 tile stage, 512 threads, 1 issue/thread ----------
__device__ __forceinline__ void stage_async64_t512(u16* dst, const u16* src, int stride,
                                                   int tid) {
  int ci = tid;  // 16B chunk index 0..511
  int r = ci >> 3, c = ci & 7;
  int sc = c ^ (r & 7);
  gld_lds16(src + (size_t)r * stride + sc * 8, dst + ci * 8);
}

__device__ __forceinline__ bf16x8 ld_frag64(const u16* lds, int rowbase, int chunkbase, int l) {
  int row = rowbase + (l & 15);
  int chunk = chunkbase + (l >> 4);
  int slot = chunk ^ (row & 7);
  return __builtin_bit_cast(bf16x8, *(const u32x4*)(lds + row * 64 + slot * 8));
}

// ---------- fused attention + causal-complement zero tail ----------
// 512 blocks x 512 threads; key-split wave pairs (R13). Pass 1 AND pass 2 both
// pairwise: one barrier + one counted WAITV per 128 keys, ring-4 K (+ ring-4 V in
// pass 2) -> 2 tiles of compute cover each staged pair's L2 latency. Q staged via
// ps (LDS 72.5KB -> 2 blocks/CU). Complementary qt sequences (R11); max-free
// softmax (R6); plain p/ao stores (R8); nt END-TAIL zeros (R14 - distributing them
// into the loop was tried twice (R15/R16) and is net-negative: the complementary
// qt balance already overlaps tail writes with other blocks' compute).
__global__ __launch_bounds__(512) void attn_kernel(const u16* __restrict__ qb,
                                                   const u16* __restrict__ kk,
                                                   const u16* __restrict__ km,
                                                   const u16* __restrict__ vkT,
                                                   const u16* __restrict__ vmT,
                                                   float* __restrict__ scores,
                                                   u16* __restrict__ ao) {
  const int fid = blockIdx.x;
  const int xcd = fid & 7, ixd = fid >> 3;  // ixd in [0,64)
  const int h = xcd * 2 + (ixd >> 5);       // 2 heads per XCD -> K/V L2-resident
  const int j = ixd & 31;
  const int a = j >> 1;
  // half 0: big,small,big,... ; half 1: small,big,small,... (complementary)
  const int qt = (((j & 1) ^ (ixd >> 5)) == 0) ? (31 - a) : a;
  const int tid = threadIdx.x, w = tid >> 6, l = tid & 63;
  const int wk = w & 3, kh = w >> 2;  // q-row group / key half
  const int nt = qt + 1;  // 64-key tiles per half
  const int NT = 2 * nt;  // always even, >= 2
  const int qrow0 = qt * 64;
  const int q16 = l & 15, c4 = l >> 4;
  const int qme = qrow0 + wk * 16 + q16;  // this lane's q-row
  const float sc2 = 0.04508422f;          // log2(e)/32

  __shared__ u16 kr[4][64 * 64];  // K ring (both passes)
  __shared__ u16 vr[4][64 * 64];  // V ring (pass 2)
  __shared__ u16 ps[64 * 64];     // Q staging, then P tile
  __shared__ float stat[128];     // per-wave lsum handoff

  auto kptr = [&](int it) {
    int hf = it >= nt;
    int t = it - (hf ? nt : 0);
    const u16* kb = hf ? km : kk;
    return kb + (size_t)(t * 64) * 1024 + h * HD_;
  };
  auto vptr = [&](int it) {
    int hf = it >= nt;
    int t = it - (hf ? nt : 0);
    const u16* vb = hf ? vmT : vkT;
    return vb + (size_t)(h * HD_) * S_ + t * 64;
  };

  // stage Q into ps (sync, swizzled write): 512 chunks, 1 per thread
  {
    int r = tid >> 3, c = tid & 7;
    u32x4 v = *(const u32x4*)(qb + (size_t)(qrow0 + r) * D_ + h * HD_ + c * 8);
    *(u32x4*)(ps + r * 64 + ((c ^ (r & 7)) * 8)) = v;
  }
  __syncthreads();  // full drain: vmcnt clean for counted waits below
  bf16x8 qA0 = ld_frag64(ps, wk * 16, 0, l);
  bf16x8 qA1 = ld_frag64(ps, wk * 16, 4, l);
  __syncthreads();  // all Q-frag reads done before ps is reused in pass 2

  // ---- pass 1: lsum only (max-free); pairwise tiles, ring-4, one barrier/128 keys ----
  float aa[4] = {0.f, 0.f, 0.f, 0.f};
  stage_async64_t512(kr[0], kptr(0), 1024, tid);
  stage_async64_t512(kr[1], kptr(1), 1024, tid);
  for (int p = 0; p < NT; p += 2) {
    WAITV(0);
    BAR(); SFENCE();
    if (p + 2 < NT) {
      stage_async64_t512(kr[(p + 2) & 3], kptr(p + 2), 1024, tid);
      stage_async64_t512(kr[(p + 3) & 3], kptr(p + 3), 1024, tid);
    }
    __builtin_amdgcn_s_setprio(1);
#pragma unroll
    for (int half = 0; half < 2; ++half) {
      int it = p + half;
      const u16* ksb = kr[it & 3];
      int domask = (it == nt - 1) || (it == NT - 1);
      int tbase = (it - (it >= nt ? nt : 0)) * 64;
      f32x4 zfv = {0.f, 0.f, 0.f, 0.f};
#pragma unroll
      for (int jf = 0; jf < 2; ++jf) {
        int kf = kh * 2 + jf;
        f32x4 z = zfv;
        z = mfma16(ld_frag64(ksb, kf * 16, 0, l), qA0, z);
        z = mfma16(ld_frag64(ksb, kf * 16, 4, l), qA1, z);
#pragma unroll
        for (int r = 0; r < 4; ++r) {
          float v = z[r];
          if (domask) {
            int key = tbase + kf * 16 + c4 * 4 + r;
            if (key > qme) v = -1e30f;  // ex2 -> 0
          }
          aa[r] += ex2(v * sc2);
        }
      }
    }
    __builtin_amdgcn_s_setprio(0);
    SFENCE();
  }
  // wave-local sum over its 32 keys, then join across the key-split pair
  float psum = (aa[0] + aa[1]) + (aa[2] + aa[3]);
  psum += __shfl_xor(psum, 16, 64);
  psum += __shfl_xor(psum, 32, 64);
  if (l < 16) stat[w * 16 + l] = psum;
  __syncthreads();  // also: all waves done with pass-1 kr reads
  const float lsum = stat[wk * 16 + q16] + stat[(wk + 4) * 16 + q16];
  const float moff = __log2f(lsum);  // p = 2^(s*sc2 - moff)

  // ---- pass 2: pairwise; recompute S (own key half), write scores, PV ----
  f32x4 zf = {0.f, 0.f, 0.f, 0.f};
  f32x4 o[4];
#pragma unroll
  for (int df = 0; df < 4; ++df) o[df] = zf;

  float* const srow0 = scores + ((size_t)h * S_ + qme) * (2 * S_) + c4 * 4;
  const int prow = wk * 16 + q16;
  const int swz8 = (q16 & 7) << 1;

  stage_async64_t512(kr[0], kptr(0), 1024, tid);
  stage_async64_t512(kr[1], kptr(1), 1024, tid);
  stage_async64_t512(vr[0], vptr(0), S_, tid);
  stage_async64_t512(vr[1], vptr(1), S_, tid);
  for (int p = 0; p < NT; p += 2) {
    // steady queue at WAITV: [S(p-4)<=4][L(p)x4][S(p-2)x4] -> WAITV(4) drains L(p)
    if (p == 0) { WAITV(0); } else { WAITV(4); }
    BAR(); SFENCE();
    if (p + 2 < NT) {  // slots (p+2)&3: freed by compute(p-2), proven by this BAR
      stage_async64_t512(kr[(p + 2) & 3], kptr(p + 2), 1024, tid);
      stage_async64_t512(kr[(p + 3) & 3], kptr(p + 3), 1024, tid);
      stage_async64_t512(vr[(p + 2) & 3], vptr(p + 2), S_, tid);
      stage_async64_t512(vr[(p + 3) & 3], vptr(p + 3), S_, tid);
    }
#pragma unroll
    for (int half = 0; half < 2; ++half) {
      int it = p + half;
      int domask = (it == nt - 1) || (it == NT - 1);
      int hf = it >= nt;
      int tbase = (it - (hf ? nt : 0)) * 64;
      float pv[8];
      __builtin_amdgcn_s_setprio(1);
#pragma unroll
      for (int jf = 0; jf < 2; ++jf) {
        int kf = kh * 2 + jf;
        f32x4 z = zf;
        z = mfma16(ld_frag64(kr[it & 3], kf * 16, 0, l), qA0, z);
        z = mfma16(ld_frag64(kr[it & 3], kf * 16, 4, l), qA1, z);
#pragma unroll
        for (int r = 0; r < 4; ++r) {
          float v = z[r];
          if (domask) {
            int key = tbase + kf * 16 + c4 * 4 + r;
            if (key > qme) v = -1e30f;
          }
          pv[jf * 4 + r] = ex2(__builtin_fmaf(v, sc2, -moff));
        }
      }
      __builtin_amdgcn_s_setprio(0);
      // scores: 2 x 16B per lane (two waves cover the row's 256B contiguous)
      float* srow = srow0 + hf * S_ + tbase;
#pragma unroll
      for (int jf = 0; jf < 2; ++jf) {
        int kf = kh * 2 + jf;
        f32x4 s4 = {pv[jf * 4], pv[jf * 4 + 1], pv[jf * 4 + 2], pv[jf * 4 + 3]};
        *(f32x4*)(srow + kf * 16) = s4;
      }
      // ps: 2 x 8B per lane, 8B-slot XOR swizzle (bijective -> pair-disjoint);
      // wave-private rows+slots -> no barrier between tiles of a pair
#pragma unroll
      for (int jf = 0; jf < 2; ++jf) {
        int kf = kh * 2 + jf;
        u16x4 pk;
#pragma unroll
        for (int r = 0; r < 4; ++r) pk[r] = f2bf(pv[jf * 4 + r]);
        int slot8 = (kf * 4 + c4) ^ swz8;
        *(u16x4*)(ps + prow * 64 + slot8 * 4) = pk;
      }
      // PV over own 32 keys: one P-frag, 4 V-frags
      __builtin_amdgcn_s_setprio(1);
      {
        bf16x8 pa = ld_frag64(ps, wk * 16, kh * 4, l);
#pragma unroll
        for (int df = 0; df < 4; ++df)
          o[df] = mfma16(ld_frag64(vr[it & 3], df * 16, kh * 4, l), pa, o[df]);
      }
      __builtin_amdgcn_s_setprio(0);
    }
    SFENCE();
  }

  // ---- join partial O across the key-split pair; kh=0 stores ao ----
  __syncthreads();                // all kr/vr/ps reads complete
  float* obuf = (float*)kr;       // 16 KB scratch
  if (kh == 1) {
#pragma unroll
    for (int df = 0; df < 4; ++df)
#pragma unroll
      for (int r = 0; r < 4; ++r)
        obuf[((wk * 4 + df) * 16 + c4 * 4 + r) * 16 + q16] = o[df][r];
  }
  __syncthreads();
  if (kh == 0) {
#pragma unroll
    for (int df = 0; df < 4; ++df) {
      u16x4 pk;
#pragma unroll
      for (int r = 0; r < 4; ++r) {
        float t = o[df][r] + obuf[((wk * 4 + df) * 16 + c4 * 4 + r) * 16 + q16];
        pk[r] = f2bf(t);
      }
      *(u16x4*)(ao + (size_t)qme * D_ + h * HD_ + df * 16 + c4 * 4) = pk;
    }
  }

  // ---- zero tail: cols [nt*64, 2048) of both halves for this block's 64 rows ----
  int zc = 2048 - nt * 64;
  if (zc > 0) {
    int vph = zc >> 2;
    f32x4 zero = {0.f, 0.f, 0.f, 0.f};
    float* base = scores + ((size_t)h * S_ + qrow0) * (2 * S_) + nt * 64;
    for (int row = 0; row < 64; ++row) {
      float* rp = base + (size_t)row * (2 * S_);
      for (int i = tid; i < vph; i += 512)
        __builtin_nontemporal_store(zero, (f32x4*)(rp + i * 4));
      for (int i = tid; i < vph; i += 512)
        __builtin_nontemporal_store(zero, (f32x4*)(rp + S_ + i * 4));
    }
  }
}

extern "C" void kernel_launch(void* const* d_in, const int* in_sizes, int n_in, void* d_out,
                              int out_size, void* d_ws, size_t ws_size, hipStream_t stream) {
  const float* hs = (const float*)d_in[0];
  const float* kn = (const float*)d_in[1];
  const float* Wq = (const float*)d_in[2];
  const float* Wkk = (const float*)d_in[3];
  const float* Wkm = (const float*)d_in[4];
  const float* Wvk = (const float*)d_in[5];
  const float* Wvm = (const float*)d_in[6];
  const float* Wo = (const float*)d_in[7];
  float* out = (float*)d_out;
  float* scores = out + (size_t)S_ * D_;

  const size_t M2 = (size_t)S_ * D_;  // 2M elems
  u16* ws = (u16*)d_ws;               // ~48 MB
  u16* hs_bf = ws;
  u16* kn_bf = hs_bf + M2;
  u16* WqT = kn_bf + M2;    // [1024][2048]
  u16* WkvkT = WqT + M2;    // [2048][1024]: rows 0-1023 Wkk^T, 1024-2047 Wvk^T
  u16* WkvmT = WkvkT + M2;  // same for mlp
  u16* WoT = WkvmT + M2;    // [1024][1024]
  u16* qb = WoT + M2 / 2;   // [2048][1024]
  u16* kk = qb + M2;        // [2048][1024] K_know
  u16* km = kk + M2;        // [2048][1024] K_mlp
  u16* vkT = km + M2;       // [1024][2048] per-head [h][hd][s]
  u16* vmT = vkT + M2;
  u16* aob = vmT + M2;

  int n4 = (int)(M2 / 4);
  prep_kernel<<<11264, 256, 0, stream>>>(hs, kn, Wq, Wkk, Wvk, Wkm, Wvm, Wo, hs_bf, kn_bf, WqT,
                                         WkvkT, WkvmT, WoT, n4);
  proj_gemm<<<768, 256, 0, stream>>>(hs_bf, kn_bf, WqT, WkvkT, WkvmT, qb, kk, km, vkT, vmT);
  attn_kernel<<<512, 512, 0, stream>>>(qb, kk, km, vkT, vmT, scores, aob);
  out_gemm<<<512, 256, 0, stream>>>(aob, WoT, out);
}